// Round 10
// baseline (160.133 us; speedup 1.0000x reference)
//
#include <hip/hip_runtime.h>
#include <float.h>

#define D    64
#define K    512
#define HW   4096      // 64*64
#define NPIX 131072    // 32*4096
#define KT   16
#define GT_S 1.2e-4f   // gap threshold in s-units (dist-gap/2); bound ~3.2e-5

// ===== MFMA-path ws layout (bytes) =====
#define OFF_CK    0u          // float ck[512]                    (2048)
#define OFF_CBFH  2048u       // ushort cbfh[64*512] frag-packed  (65536)
#define OFF_CBFL  67584u      // ushort cbfl[64*512]              (65536)
#define OFF_T1    133120u     // float t1[NPIX]                   (524288)
#define OFF_XH    657408u     // ushort xh[8][NPIX][8] chunk-major(16777216)
#define OFF_XL    17434624u   // ushort xl[8][NPIX][8]            (16777216)
#define OFF_IDX   34211840u   // int idx[NPIX]                    (524288)
#define OFF_CNT   34736128u   // int count                        (4)
#define OFF_LIST  34736132u   // int list[NPIX]                   (524288)
#define OFF_CKQ   35260420u   // float ckq[512] = -ck/2           (2048)
#define WS_NEED   35262468u

typedef __attribute__((ext_vector_type(8))) short bf16x8;
typedef __attribute__((ext_vector_type(4))) float f32x4;

__device__ __forceinline__ unsigned short bf16_rne(float f) {
    unsigned u = __float_as_uint(f);
    return (unsigned short)((u + 0x7FFFu + ((u >> 16) & 1u)) >> 16);
}
__device__ __forceinline__ float bf16_back(unsigned short h) {
    return __uint_as_float(((unsigned)h) << 16);
}

// ck[k] = numpy sum(cb*cb, axis=0): sequential adds over d, squares pre-rounded.
// ckq[k] = -ck/2 (exact). Packs cb into bf16 hi/lo fragment layout:
//   pos(tile=k>>4, ks=d>>5, g=(d>>3)&3, n=k&15, j=d&7) = (tile*2+ks)*512 + g*128 + n*8 + j
__global__ void vq_prep_m(const float* __restrict__ cb, float* __restrict__ ck,
                          float* __restrict__ ckq,
                          unsigned short* __restrict__ cbfh, unsigned short* __restrict__ cbfl,
                          int* __restrict__ count) {
#pragma clang fp contract(off)
    const int k = blockIdx.x * 128 + threadIdx.x;
    if (k == 0) *count = 0;
    float s = 0.f;
    for (int d = 0; d < D; ++d) {
        const float e  = cb[d * K + k];
        const float e2 = e * e;
        s = s + e2;
        const unsigned short h = bf16_rne(e);
        const unsigned short l = bf16_rne(e - bf16_back(h));
        const int pos = ((k >> 4) * 2 + (d >> 5)) * 512 + ((d >> 3) & 3) * 128 + (k & 15) * 8 + (d & 7);
        cbfh[pos] = h;
        cbfl[pos] = l;
    }
    ck[k]  = s;
    ckq[k] = -0.5f * s;
}

// Per pixel: exact numpy t1 (pairwise 8-acc) + bf16 hi/lo split of x.
// Output layout CHUNK-MAJOR [c][p][8] so stores are dense uint4 across threads.
__global__ __launch_bounds__(256) void vq_pre(const float* __restrict__ enc,
        float* __restrict__ t1a, unsigned short* __restrict__ xh,
        unsigned short* __restrict__ xl) {
    const int p  = blockIdx.x * 256 + threadIdx.x;
    const int b  = p >> 12;
    const int hw = p & 4095;
    const float* ep = enc + (size_t)b * (D * HW) + hw;
    float x[D];
    #pragma unroll
    for (int d = 0; d < D; ++d) x[d] = ep[(size_t)d * HW];

    float t1;
    {
#pragma clang fp contract(off)
        float r[8];
        #pragma unroll
        for (int j = 0; j < 8; ++j) r[j] = x[j] * x[j];
        #pragma unroll
        for (int i = 8; i < 64; i += 8) {
            #pragma unroll
            for (int j = 0; j < 8; ++j) {
                const float v2 = x[i + j] * x[i + j];
                r[j] = r[j] + v2;
            }
        }
        t1 = ((r[0] + r[1]) + (r[2] + r[3])) + ((r[4] + r[5]) + (r[6] + r[7]));
    }
    t1a[p] = t1;

    #pragma unroll
    for (int c = 0; c < 8; ++c) {
        unsigned short hs[8], ls[8];
        #pragma unroll
        for (int j = 0; j < 8; ++j) {
            const float v = x[c * 8 + j];
            const unsigned short h = bf16_rne(v);
            hs[j] = h;
            ls[j] = bf16_rne(v - bf16_back(h));
        }
        uint4 hv, lv;
        hv.x = (unsigned)hs[0] | ((unsigned)hs[1] << 16);
        hv.y = (unsigned)hs[2] | ((unsigned)hs[3] << 16);
        hv.z = (unsigned)hs[4] | ((unsigned)hs[5] << 16);
        hv.w = (unsigned)hs[6] | ((unsigned)hs[7] << 16);
        lv.x = (unsigned)ls[0] | ((unsigned)ls[1] << 16);
        lv.y = (unsigned)ls[2] | ((unsigned)ls[3] << 16);
        lv.z = (unsigned)ls[4] | ((unsigned)ls[5] << 16);
        lv.w = (unsigned)ls[6] | ((unsigned)ls[7] << 16);
        *reinterpret_cast<uint4*>(xh + ((size_t)c * NPIX + p) * 8) = hv;
        *reinterpret_cast<uint4*>(xl + ((size_t)c * NPIX + p) * 8) = lv;
    }
}

// MFMA filter v2: 32 pixels/wave (2 groups share B), B-frags direct from L2
// (256 KB, L2-resident -- LDS staging was pure overhead), double-buffered
// 2-tile pipeline, ck folded into MFMA C-operand, 6-op/pair tracking with NO
// tie-break logic (any tie => gap 0 => refine resolves exactly).
#define LOADB(S, T) do {                                                   \
    const int _o = (T) * 1024;                                             \
    bh0##S = *(const bf16x8*)(cbfh_l + _o);                                \
    bh1##S = *(const bf16x8*)(cbfh_l + _o + 512);                          \
    bl0##S = *(const bf16x8*)(cbfl_l + _o);                                \
    bl1##S = *(const bf16x8*)(cbfl_l + _o + 512);                          \
    ck##S  = ckq_l[(T) * 16];                                              \
} while (0)

#define PROCESS(S, T) do {                                                 \
    const f32x4 CKv = {ck##S, ck##S, ck##S, ck##S};                        \
    f32x4 p0, p1, q0, q1;                                                  \
    p0 = __builtin_amdgcn_mfma_f32_16x16x32_bf16(al00, bh0##S, CKv, 0,0,0);\
    p0 = __builtin_amdgcn_mfma_f32_16x16x32_bf16(ah00, bl0##S, p0, 0,0,0); \
    p0 = __builtin_amdgcn_mfma_f32_16x16x32_bf16(ah00, bh0##S, p0, 0,0,0); \
    p1 = __builtin_amdgcn_mfma_f32_16x16x32_bf16(al01, bh1##S, Z4, 0,0,0); \
    p1 = __builtin_amdgcn_mfma_f32_16x16x32_bf16(ah01, bl1##S, p1, 0,0,0); \
    p1 = __builtin_amdgcn_mfma_f32_16x16x32_bf16(ah01, bh1##S, p1, 0,0,0); \
    q0 = __builtin_amdgcn_mfma_f32_16x16x32_bf16(al10, bh0##S, CKv, 0,0,0);\
    q0 = __builtin_amdgcn_mfma_f32_16x16x32_bf16(ah10, bl0##S, q0, 0,0,0); \
    q0 = __builtin_amdgcn_mfma_f32_16x16x32_bf16(ah10, bh0##S, q0, 0,0,0); \
    q1 = __builtin_amdgcn_mfma_f32_16x16x32_bf16(al11, bh1##S, Z4, 0,0,0); \
    q1 = __builtin_amdgcn_mfma_f32_16x16x32_bf16(ah11, bl1##S, q1, 0,0,0); \
    q1 = __builtin_amdgcn_mfma_f32_16x16x32_bf16(ah11, bh1##S, q1, 0,0,0); \
    _Pragma("unroll")                                                      \
    for (int i = 0; i < 4; ++i) {                                          \
        const float s0 = p0[i] + p1[i];                                    \
        const bool g0 = s0 > best[i];                                      \
        bi[i]    = g0 ? (T) : bi[i];                                       \
        best2[i] = fmaxf(best2[i], fminf(best[i], s0));                    \
        best[i]  = fmaxf(best[i], s0);                                     \
        const float s1 = q0[i] + q1[i];                                    \
        const bool g1 = s1 > best[4 + i];                                  \
        bi[4 + i]    = g1 ? (T) : bi[4 + i];                               \
        best2[4 + i] = fmaxf(best2[4 + i], fminf(best[4 + i], s1));        \
        best[4 + i]  = fmaxf(best[4 + i], s1);                             \
    }                                                                      \
} while (0)

__global__ __launch_bounds__(256) void vq_mfma(const unsigned short* __restrict__ xh,
        const unsigned short* __restrict__ xl, const unsigned short* __restrict__ cbfh,
        const unsigned short* __restrict__ cbfl, const float* __restrict__ ckq,
        int* __restrict__ idx, int* __restrict__ count, int* __restrict__ list) {
    const int t    = threadIdx.x;
    const int lane = t & 63;
    const int wu   = __builtin_amdgcn_readfirstlane(t >> 6);
    const int P0   = blockIdx.x * 128 + wu * 32;
    const int n    = lane & 15;          // B col = code-in-tile; A row
    const int g    = lane >> 4;          // k-chunk / D row group

    // A-frags: pg {0,1} x kstep {0,1}, hi/lo
    const size_t a00 = ((size_t)g       * NPIX + (P0 + n))      * 8;
    const size_t a01 = ((size_t)(g + 4) * NPIX + (P0 + n))      * 8;
    const size_t a10 = ((size_t)g       * NPIX + (P0 + 16 + n)) * 8;
    const size_t a11 = ((size_t)(g + 4) * NPIX + (P0 + 16 + n)) * 8;
    const bf16x8 ah00 = *(const bf16x8*)(xh + a00);
    const bf16x8 ah01 = *(const bf16x8*)(xh + a01);
    const bf16x8 ah10 = *(const bf16x8*)(xh + a10);
    const bf16x8 ah11 = *(const bf16x8*)(xh + a11);
    const bf16x8 al00 = *(const bf16x8*)(xl + a00);
    const bf16x8 al01 = *(const bf16x8*)(xl + a01);
    const bf16x8 al10 = *(const bf16x8*)(xl + a10);
    const bf16x8 al11 = *(const bf16x8*)(xl + a11);

    const unsigned short* cbfh_l = cbfh + g * 128 + n * 8;
    const unsigned short* cbfl_l = cbfl + g * 128 + n * 8;
    const float*          ckq_l  = ckq + n;
    const f32x4 Z4 = {0.f, 0.f, 0.f, 0.f};

    float best[8], best2[8];
    int bi[8];
    #pragma unroll
    for (int i = 0; i < 8; ++i) { best[i] = -FLT_MAX; best2[i] = -FLT_MAX; bi[i] = 0; }

    bf16x8 bh0a, bh1a, bl0a, bl1a; float cka;
    bf16x8 bh0b, bh1b, bl0b, bl1b; float ckb;
    LOADB(a, 0);
    #pragma unroll 1
    for (int t2 = 0; t2 < 16; ++t2) {
        const int tA = 2 * t2, tB = 2 * t2 + 1;
        LOADB(b, tB);
        PROCESS(a, tA);
        LOADB(a, (tB + 1) & 31);    // wraps to 0 on last iter (harmless)
        PROCESS(b, tB);
    }

    // encode full code index k = tile*16 + n, then merge across the 16 lanes
    #pragma unroll
    for (int i = 0; i < 8; ++i) bi[i] = bi[i] * 16 + n;
    #pragma unroll
    for (int off = 1; off < 16; off <<= 1) {
        #pragma unroll
        for (int i = 0; i < 8; ++i) {
            const float ob  = __shfl_xor(best[i],  off, 16);
            const float ob2 = __shfl_xor(best2[i], off, 16);
            const int   obi = __shfl_xor(bi[i],    off, 16);
            const bool  gt  = ob > best[i];
            const float mn  = fminf(best[i], ob);
            const float b2w = gt ? ob2 : best2[i];
            best2[i] = fmaxf(mn, b2w);
            bi[i]    = gt ? obi : bi[i];
            best[i]  = fmaxf(best[i], ob);
        }
    }

    if (n == 0) {
        #pragma unroll
        for (int sl = 0; sl < 8; ++sl) {
            const int pg = sl >> 2, i = sl & 3;
            const int p  = P0 + pg * 16 + g * 4 + i;
            idx[p] = bi[sl];
            if (best[sl] - best2[sl] < GT_S) {
                const int slot = atomicAdd(count, 1);
                list[slot] = p;
            }
        }
    }
}

// Exact numpy rescore for near-tie pixels (round-9 version, proven).
__global__ __launch_bounds__(256) void vq_refine(const float* __restrict__ enc,
        const float* __restrict__ cb, const float* __restrict__ ck,
        const float* __restrict__ t1a, const int* __restrict__ count,
        const int* __restrict__ list, int* __restrict__ idx) {
    const int nref = *count;
    const int lane = threadIdx.x & 63;
    const int gw   = (int)((blockIdx.x * blockDim.x + threadIdx.x) >> 6);
    const int nw   = (int)((gridDim.x * blockDim.x) >> 6);
    for (int r = gw; r < nref; r += nw) {
        const int p  = list[r];
        const int b  = p >> 12;
        const int hw = p & 4095;
        const float* xp = enc + (size_t)b * (D * HW) + hw;
        const float xown = xp[(size_t)lane * HW];
        const float t1 = t1a[p];
        float acc[8];
        #pragma unroll
        for (int j = 0; j < 8; ++j) acc[j] = 0.f;
        const float* cbl = cb + lane * 8;
        #pragma unroll 16
        for (int d = 0; d < D; ++d) {
            const float xd = __shfl(xown, d);
            const float4 c0 = *(const float4*)(cbl + (size_t)d * K);
            const float4 c1 = *(const float4*)(cbl + (size_t)d * K + 4);
            acc[0] = fmaf(xd, c0.x, acc[0]);
            acc[1] = fmaf(xd, c0.y, acc[1]);
            acc[2] = fmaf(xd, c0.z, acc[2]);
            acc[3] = fmaf(xd, c0.w, acc[3]);
            acc[4] = fmaf(xd, c1.x, acc[4]);
            acc[5] = fmaf(xd, c1.y, acc[5]);
            acc[6] = fmaf(xd, c1.z, acc[6]);
            acc[7] = fmaf(xd, c1.w, acc[7]);
        }
        float bv = FLT_MAX;
        int bI = 0x7fffffff;
        #pragma unroll
        for (int j = 0; j < 8; ++j) {
            const float u    = fmaf(-2.0f, acc[j], t1);
            const float dist = u + ck[lane * 8 + j];
            if (dist < bv) { bv = dist; bI = lane * 8 + j; }
        }
        #pragma unroll
        for (int off = 32; off > 0; off >>= 1) {
            const float ov = __shfl_down(bv, off);
            const int   oi = __shfl_down(bI, off);
            if (ov < bv || (ov == bv && oi < bI)) { bv = ov; bI = oi; }
        }
        if (lane == 0) idx[p] = bI;
    }
}

// ===== scalar fallback (round-7, proven 128 us) =====
__global__ void vq_prep_s(const float* __restrict__ cb, float* __restrict__ ck) {
#pragma clang fp contract(off)
    const int k = threadIdx.x;
    float s = 0.f;
    for (int d = 0; d < D; ++d) {
        const float e  = cb[d * K + k];
        const float e2 = e * e;
        s = s + e2;
    }
    ck[k] = s;
}

__global__ __launch_bounds__(256, 8) void vq_main_s(const float* __restrict__ enc,
        const float* __restrict__ cb, const float* __restrict__ ck,
        int* __restrict__ idx) {
    __shared__ float xs[D][64];
    __shared__ float bvs[3][64];
    __shared__ int   bis[3][64];

    const int t    = threadIdx.x;
    const int lane = t & 63;
    const int wu   = __builtin_amdgcn_readfirstlane(t >> 6);
    const int base = blockIdx.x * 64;
    const int b    = base >> 12;
    const int hw0  = base & 4095;
    const float* ep = enc + (size_t)b * (D * HW) + hw0;

    #pragma unroll
    for (int i = 0; i < 16; ++i) {
        const int id  = t + i * 256;
        xs[id >> 6][id & 63] = ep[(size_t)(id >> 6) * HW + (id & 63)];
    }
    __syncthreads();

    float t1;
    {
#pragma clang fp contract(off)
        float r[8];
        #pragma unroll
        for (int j = 0; j < 8; ++j) { const float v = xs[j][lane]; r[j] = v * v; }
        #pragma unroll
        for (int i = 8; i < 64; i += 8) {
            #pragma unroll
            for (int j = 0; j < 8; ++j) {
                const float v = xs[i + j][lane]; const float v2 = v * v; r[j] = r[j] + v2;
            }
        }
        t1 = ((r[0] + r[1]) + (r[2] + r[3])) + ((r[4] + r[5]) + (r[6] + r[7]));
    }

    float best = FLT_MAX;
    int besti  = 0x7fffffff;
    const int kbase = wu * (K / 4);
    #pragma unroll 1
    for (int tt = 0; tt < 8; ++tt) {
        const int k0 = kbase + tt * KT;
        float acc[KT];
        #pragma unroll
        for (int j = 0; j < KT; ++j) acc[j] = 0.f;
        #pragma unroll 8
        for (int d = 0; d < D; ++d) {
            const float xv = xs[d][lane];
            const float* cbrow = cb + d * K + k0;
            #pragma unroll
            for (int j = 0; j < KT; ++j) acc[j] = fmaf(xv, cbrow[j], acc[j]);
        }
        #pragma unroll
        for (int j = 0; j < KT; ++j) {
            const float u    = fmaf(-2.0f, acc[j], t1);
            const float dist = u + ck[k0 + j];
            if (dist < best) { best = dist; besti = k0 + j; }
        }
    }

    if (wu > 0) { bvs[wu - 1][lane] = best; bis[wu - 1][lane] = besti; }
    __syncthreads();
    if (wu == 0) {
        #pragma unroll
        for (int q = 0; q < 3; ++q) {
            const float ov = bvs[q][lane];
            const int   oi = bis[q][lane];
            if (ov < best) { best = ov; besti = oi; }
        }
        idx[base + lane] = besti;
    }
}

__global__ void vq_out(const float* __restrict__ cb, const int* __restrict__ idx,
                       float* __restrict__ out) {
    const int o = (blockIdx.x * 256 + threadIdx.x) * 4;
    const int d = (o >> 12) & 63;
    const int bhw = ((o >> 18) << 12) | (o & 4095);
    const int4 iv = *reinterpret_cast<const int4*>(idx + bhw);
    float4 v;
    v.x = cb[d * K + iv.x];
    v.y = cb[d * K + iv.y];
    v.z = cb[d * K + iv.z];
    v.w = cb[d * K + iv.w];
    *reinterpret_cast<float4*>(out + o) = v;
}

extern "C" void kernel_launch(void* const* d_in, const int* in_sizes, int n_in,
                              void* d_out, int out_size, void* d_ws, size_t ws_size,
                              hipStream_t stream) {
    const float* enc = (const float*)d_in[0];
    const float* cb  = (const float*)d_in[1];
    float* out = (float*)d_out;
    char* ws = (char*)d_ws;

    if (ws_size >= (size_t)WS_NEED) {
        float*          ck   = (float*)(ws + OFF_CK);
        float*          ckq  = (float*)(ws + OFF_CKQ);
        unsigned short* cbfh = (unsigned short*)(ws + OFF_CBFH);
        unsigned short* cbfl = (unsigned short*)(ws + OFF_CBFL);
        float*          t1a  = (float*)(ws + OFF_T1);
        unsigned short* xh   = (unsigned short*)(ws + OFF_XH);
        unsigned short* xl   = (unsigned short*)(ws + OFF_XL);
        int*            idx  = (int*)(ws + OFF_IDX);
        int*            cnt  = (int*)(ws + OFF_CNT);
        int*            list = (int*)(ws + OFF_LIST);

        vq_prep_m<<<4, 128, 0, stream>>>(cb, ck, ckq, cbfh, cbfl, cnt);
        vq_pre<<<NPIX / 256, 256, 0, stream>>>(enc, t1a, xh, xl);
        vq_mfma<<<NPIX / 128, 256, 0, stream>>>(xh, xl, cbfh, cbfl, ckq, idx, cnt, list);
        vq_refine<<<1024, 256, 0, stream>>>(enc, cb, ck, t1a, cnt, list, idx);
        vq_out<<<out_size / 1024, 256, 0, stream>>>(cb, idx, out);
    } else {
        float* ck  = (float*)ws;
        int*   idx = (int*)(ws + 2048);
        vq_prep_s<<<1, K, 0, stream>>>(cb, ck);
        vq_main_s<<<NPIX / 64, 256, 0, stream>>>(enc, cb, ck, idx);
        vq_out<<<out_size / 1024, 256, 0, stream>>>(cb, idx, out);
    }
}

// Round 11
// 154.728 us; speedup vs baseline: 1.0349x; 1.0349x over previous
//
#include <hip/hip_runtime.h>
#include <float.h>

#define D    64
#define K    512
#define HW   4096      // 64*64
#define NPIX 131072    // 32*4096
#define KT   16
#define GT_S 1.2e-4f   // gap threshold in s-units; |s_mfma - s_numpy| bound ~1e-5

// ===== MFMA-path ws layout (bytes) =====
#define OFF_CK    0u          // float ck[512]
#define OFF_CBFH  2048u       // ushort cbfh[64*512] frag-packed
#define OFF_CBFL  67584u      // ushort cbfl[64*512]
#define OFF_IDX   34211840u   // int idx[NPIX]
#define OFF_CNT   34736128u   // int count
#define OFF_LIST  34736132u   // int list[NPIX]
#define OFF_CKQ   35260420u   // float ckq[512] = -ck/2
#define WS_NEED   35262468u

typedef __attribute__((ext_vector_type(8))) short bf16x8;
typedef __attribute__((ext_vector_type(4))) float f32x4;

__device__ __forceinline__ unsigned short bf16_rne(float f) {
    unsigned u = __float_as_uint(f);
    return (unsigned short)((u + 0x7FFFu + ((u >> 16) & 1u)) >> 16);
}
__device__ __forceinline__ float bf16_back(unsigned short h) {
    return __uint_as_float(((unsigned)h) << 16);
}

// ck[k] = numpy sum(cb*cb, axis=0): sequential adds over d, squares pre-rounded.
// ckq[k] = -ck/2. Packs cb into bf16 hi/lo fragment layout:
//   pos(tile=k>>4, ks=d>>5, g=(d>>3)&3, n=k&15, j=d&7) = (tile*2+ks)*512 + g*128 + n*8 + j
__global__ void vq_prep_m(const float* __restrict__ cb, float* __restrict__ ck,
                          float* __restrict__ ckq,
                          unsigned short* __restrict__ cbfh, unsigned short* __restrict__ cbfl,
                          int* __restrict__ count) {
#pragma clang fp contract(off)
    const int k = blockIdx.x * 128 + threadIdx.x;
    if (k == 0) *count = 0;
    float s = 0.f;
    for (int d = 0; d < D; ++d) {
        const float e  = cb[d * K + k];
        const float e2 = e * e;
        s = s + e2;
        const unsigned short h = bf16_rne(e);
        const unsigned short l = bf16_rne(e - bf16_back(h));
        const int pos = ((k >> 4) * 2 + (d >> 5)) * 512 + ((d >> 3) & 3) * 128 + (k & 15) * 8 + (d & 7);
        cbfh[pos] = h;
        cbfl[pos] = l;
    }
    ck[k]  = s;
    ckq[k] = -0.5f * s;
}

// MFMA filter v3: 64 pixels/wave (4 pixel-groups share every B-frag), A-frags
// loaded DIRECTLY from enc and converted to bf16 hi/lo in-register
// (v_cvt_pk_bf16_f32) -- the xh/xl HBM round-trip is gone. B-frags from L2
// with a/b double-buffer; per-tile compute (~310 cyc) >> L2 latency.
#define LOADB(S, T) do {                                                   \
    const int _o = (T) * 1024;                                             \
    h0##S = *(const bf16x8*)(cbfh_l + _o);                                 \
    h1##S = *(const bf16x8*)(cbfh_l + _o + 512);                           \
    l0##S = *(const bf16x8*)(cbfl_l + _o);                                 \
    l1##S = *(const bf16x8*)(cbfl_l + _o + 512);                           \
    ck##S = ckq_l[(T) * 16];                                               \
} while (0)

#define PROCESS(S, T) do {                                                 \
    _Pragma("unroll")                                                      \
    for (int pg = 0; pg < 4; ++pg) {                                       \
        f32x4 c0 = {ck##S, ck##S, ck##S, ck##S};                           \
        c0 = __builtin_amdgcn_mfma_f32_16x16x32_bf16(                      \
                __builtin_bit_cast(bf16x8, AL[pg][0]), h0##S, c0, 0,0,0);  \
        c0 = __builtin_amdgcn_mfma_f32_16x16x32_bf16(                      \
                __builtin_bit_cast(bf16x8, AH[pg][0]), l0##S, c0, 0,0,0);  \
        c0 = __builtin_amdgcn_mfma_f32_16x16x32_bf16(                      \
                __builtin_bit_cast(bf16x8, AH[pg][0]), h0##S, c0, 0,0,0);  \
        f32x4 c1 = {0.f, 0.f, 0.f, 0.f};                                   \
        c1 = __builtin_amdgcn_mfma_f32_16x16x32_bf16(                      \
                __builtin_bit_cast(bf16x8, AL[pg][1]), h1##S, c1, 0,0,0);  \
        c1 = __builtin_amdgcn_mfma_f32_16x16x32_bf16(                      \
                __builtin_bit_cast(bf16x8, AH[pg][1]), l1##S, c1, 0,0,0);  \
        c1 = __builtin_amdgcn_mfma_f32_16x16x32_bf16(                      \
                __builtin_bit_cast(bf16x8, AH[pg][1]), h1##S, c1, 0,0,0);  \
        _Pragma("unroll")                                                  \
        for (int i = 0; i < 4; ++i) {                                      \
            const float s = c0[i] + c1[i];                                 \
            const int sl = pg * 4 + i;                                     \
            const bool gt = s > best[sl];                                  \
            bi[sl]    = gt ? (T) : bi[sl];                                 \
            best2[sl] = fmaxf(best2[sl], fminf(best[sl], s));              \
            best[sl]  = fmaxf(best[sl], s);                                \
        }                                                                  \
    }                                                                      \
} while (0)

__global__ __launch_bounds__(256) void vq_mfma(const float* __restrict__ enc,
        const unsigned short* __restrict__ cbfh, const unsigned short* __restrict__ cbfl,
        const float* __restrict__ ckq, int* __restrict__ idx,
        int* __restrict__ count, int* __restrict__ list) {
    const int t    = threadIdx.x;
    const int lane = t & 63;
    const int wu   = __builtin_amdgcn_readfirstlane(t >> 6);
    const int P0   = blockIdx.x * 256 + wu * 64;
    const int n    = lane & 15;          // A row = pixel-in-group; B col = code-in-tile
    const int g    = lane >> 4;          // k-chunk / D row group

    // ---- A-frags straight from enc, bf16 hi/lo split in-register ----
    const float* ep = enc + (size_t)(P0 >> 12) * (D * HW);
    const int hwp = (P0 & 4095) + n;
    uint4 AH[4][2], AL[4][2];
    #pragma unroll
    for (int pg = 0; pg < 4; ++pg) {
        #pragma unroll
        for (int ks = 0; ks < 2; ++ks) {
            float raw[8];
            #pragma unroll
            for (int j = 0; j < 8; ++j)
                raw[j] = ep[(size_t)(ks * 32 + g * 8 + j) * HW + hwp + pg * 16];
            uint4 h4, l4;
            #pragma unroll
            for (int jj = 0; jj < 4; ++jj) {
                unsigned hp, lp;
                asm("v_cvt_pk_bf16_f32 %0, %1, %2"
                    : "=v"(hp) : "v"(raw[2 * jj]), "v"(raw[2 * jj + 1]));
                const float b0 = __uint_as_float(hp << 16);
                const float b1 = __uint_as_float(hp & 0xffff0000u);
                const float r0 = raw[2 * jj] - b0;
                const float r1 = raw[2 * jj + 1] - b1;
                asm("v_cvt_pk_bf16_f32 %0, %1, %2"
                    : "=v"(lp) : "v"(r0), "v"(r1));
                (&h4.x)[jj] = hp;
                (&l4.x)[jj] = lp;
            }
            AH[pg][ks] = h4;
            AL[pg][ks] = l4;
        }
    }

    const unsigned short* cbfh_l = cbfh + g * 128 + n * 8;
    const unsigned short* cbfl_l = cbfl + g * 128 + n * 8;
    const float*          ckq_l  = ckq + n;

    float best[16], best2[16];
    int bi[16];
    #pragma unroll
    for (int i = 0; i < 16; ++i) { best[i] = -FLT_MAX; best2[i] = -FLT_MAX; bi[i] = 0; }

    bf16x8 h0a, h1a, l0a, l1a; float cka;
    bf16x8 h0b, h1b, l0b, l1b; float ckb;
    LOADB(a, 0);
    #pragma unroll 1
    for (int t2 = 0; t2 < 16; ++t2) {
        const int tA = 2 * t2, tB = 2 * t2 + 1;
        LOADB(b, tB);
        PROCESS(a, tA);
        LOADB(a, (tB + 1) & 31);    // wraps to 0 on last iter (never processed)
        PROCESS(b, tB);
    }

    // encode full code index k = tile*16 + n, then merge across the 16 lanes
    #pragma unroll
    for (int i = 0; i < 16; ++i) bi[i] = bi[i] * 16 + n;
    #pragma unroll
    for (int off = 1; off < 16; off <<= 1) {
        #pragma unroll
        for (int i = 0; i < 16; ++i) {
            const float ob  = __shfl_xor(best[i],  off, 16);
            const float ob2 = __shfl_xor(best2[i], off, 16);
            const int   obi = __shfl_xor(bi[i],    off, 16);
            const bool  gt  = ob > best[i];
            const float mn  = fminf(best[i], ob);
            const float b2w = gt ? ob2 : best2[i];
            best2[i] = fmaxf(mn, b2w);
            bi[i]    = gt ? obi : bi[i];
            best[i]  = fmaxf(best[i], ob);
        }
    }

    if (n == 0) {
        #pragma unroll
        for (int sl = 0; sl < 16; ++sl) {
            const int pg = sl >> 2, i = sl & 3;
            const int p  = P0 + pg * 16 + g * 4 + i;
            idx[p] = bi[sl];
            if (best[sl] - best2[sl] < GT_S) {
                const int slot = atomicAdd(count, 1);
                list[slot] = p;
            }
        }
    }
}

// Exact numpy rescore for near-tie pixels; computes its own numpy-exact t1
// (r[j] sequential chain + fixed tree) via lane gathers -- no t1a pass needed.
__global__ __launch_bounds__(256) void vq_refine(const float* __restrict__ enc,
        const float* __restrict__ cb, const float* __restrict__ ck,
        const int* __restrict__ count, const int* __restrict__ list,
        int* __restrict__ idx) {
    const int nref = *count;
    const int lane = threadIdx.x & 63;
    const int gw   = (int)((blockIdx.x * blockDim.x + threadIdx.x) >> 6);
    const int nw   = (int)((gridDim.x * blockDim.x) >> 6);
    for (int r = gw; r < nref; r += nw) {
        const int p  = list[r];
        const int b  = p >> 12;
        const int hw = p & 4095;
        const float* xp = enc + (size_t)b * (D * HW) + hw;
        const float xown = xp[(size_t)lane * HW];   // lane holds x[lane]

        // t1: numpy pairwise n=64 path, bit-exact. r[j] = sum_i x[8i+j]^2
        // (sequential i, squares pre-rounded), tree ((r0+r1)+(r2+r3))+((r4+r5)+(r6+r7)).
        float t1;
        {
#pragma clang fp contract(off)
            const int jl = lane & 7;
            float rj;
            {
                const float v = __shfl(xown, jl);
                rj = v * v;
            }
            #pragma unroll
            for (int i = 1; i < 8; ++i) {
                const float v  = __shfl(xown, i * 8 + jl);
                const float v2 = v * v;
                rj = rj + v2;
            }
            const float a  = rj + __shfl_xor(rj, 1);   // r_j + r_{j^1}
            const float bb = a + __shfl_xor(a, 2);     // (r0+r1)+(r2+r3)
            t1 = bb + __shfl_xor(bb, 4);               // + ((r4+r5)+(r6+r7))
        }

        float acc[8];
        #pragma unroll
        for (int j = 0; j < 8; ++j) acc[j] = 0.f;
        const float* cbl = cb + lane * 8;
        #pragma unroll 16
        for (int d = 0; d < D; ++d) {
            const float xd = __shfl(xown, d);
            const float4 c0 = *(const float4*)(cbl + (size_t)d * K);
            const float4 c1 = *(const float4*)(cbl + (size_t)d * K + 4);
            acc[0] = fmaf(xd, c0.x, acc[0]);
            acc[1] = fmaf(xd, c0.y, acc[1]);
            acc[2] = fmaf(xd, c0.z, acc[2]);
            acc[3] = fmaf(xd, c0.w, acc[3]);
            acc[4] = fmaf(xd, c1.x, acc[4]);
            acc[5] = fmaf(xd, c1.y, acc[5]);
            acc[6] = fmaf(xd, c1.z, acc[6]);
            acc[7] = fmaf(xd, c1.w, acc[7]);
        }
        float bv = FLT_MAX;
        int bI = 0x7fffffff;
        #pragma unroll
        for (int j = 0; j < 8; ++j) {
            const float u    = fmaf(-2.0f, acc[j], t1);
            const float dist = u + ck[lane * 8 + j];
            if (dist < bv) { bv = dist; bI = lane * 8 + j; }
        }
        #pragma unroll
        for (int off = 32; off > 0; off >>= 1) {
            const float ov = __shfl_down(bv, off);
            const int   oi = __shfl_down(bI, off);
            if (ov < bv || (ov == bv && oi < bI)) { bv = ov; bI = oi; }
        }
        if (lane == 0) idx[p] = bI;
    }
}

// ===== scalar fallback (round-7, proven 128 us) =====
__global__ void vq_prep_s(const float* __restrict__ cb, float* __restrict__ ck) {
#pragma clang fp contract(off)
    const int k = threadIdx.x;
    float s = 0.f;
    for (int d = 0; d < D; ++d) {
        const float e  = cb[d * K + k];
        const float e2 = e * e;
        s = s + e2;
    }
    ck[k] = s;
}

__global__ __launch_bounds__(256, 8) void vq_main_s(const float* __restrict__ enc,
        const float* __restrict__ cb, const float* __restrict__ ck,
        int* __restrict__ idx) {
    __shared__ float xs[D][64];
    __shared__ float bvs[3][64];
    __shared__ int   bis[3][64];

    const int t    = threadIdx.x;
    const int lane = t & 63;
    const int wu   = __builtin_amdgcn_readfirstlane(t >> 6);
    const int base = blockIdx.x * 64;
    const int b    = base >> 12;
    const int hw0  = base & 4095;
    const float* ep = enc + (size_t)b * (D * HW) + hw0;

    #pragma unroll
    for (int i = 0; i < 16; ++i) {
        const int id  = t + i * 256;
        xs[id >> 6][id & 63] = ep[(size_t)(id >> 6) * HW + (id & 63)];
    }
    __syncthreads();

    float t1;
    {
#pragma clang fp contract(off)
        float r[8];
        #pragma unroll
        for (int j = 0; j < 8; ++j) { const float v = xs[j][lane]; r[j] = v * v; }
        #pragma unroll
        for (int i = 8; i < 64; i += 8) {
            #pragma unroll
            for (int j = 0; j < 8; ++j) {
                const float v = xs[i + j][lane]; const float v2 = v * v; r[j] = r[j] + v2;
            }
        }
        t1 = ((r[0] + r[1]) + (r[2] + r[3])) + ((r[4] + r[5]) + (r[6] + r[7]));
    }

    float best = FLT_MAX;
    int besti  = 0x7fffffff;
    const int kbase = wu * (K / 4);
    #pragma unroll 1
    for (int tt = 0; tt < 8; ++tt) {
        const int k0 = kbase + tt * KT;
        float acc[KT];
        #pragma unroll
        for (int j = 0; j < KT; ++j) acc[j] = 0.f;
        #pragma unroll 8
        for (int d = 0; d < D; ++d) {
            const float xv = xs[d][lane];
            const float* cbrow = cb + d * K + k0;
            #pragma unroll
            for (int j = 0; j < KT; ++j) acc[j] = fmaf(xv, cbrow[j], acc[j]);
        }
        #pragma unroll
        for (int j = 0; j < KT; ++j) {
            const float u    = fmaf(-2.0f, acc[j], t1);
            const float dist = u + ck[k0 + j];
            if (dist < best) { best = dist; besti = k0 + j; }
        }
    }

    if (wu > 0) { bvs[wu - 1][lane] = best; bis[wu - 1][lane] = besti; }
    __syncthreads();
    if (wu == 0) {
        #pragma unroll
        for (int q = 0; q < 3; ++q) {
            const float ov = bvs[q][lane];
            const int   oi = bis[q][lane];
            if (ov < best) { best = ov; besti = oi; }
        }
        idx[base + lane] = besti;
    }
}

__global__ void vq_out(const float* __restrict__ cb, const int* __restrict__ idx,
                       float* __restrict__ out) {
    const int o = (blockIdx.x * 256 + threadIdx.x) * 4;
    const int d = (o >> 12) & 63;
    const int bhw = ((o >> 18) << 12) | (o & 4095);
    const int4 iv = *reinterpret_cast<const int4*>(idx + bhw);
    float4 v;
    v.x = cb[d * K + iv.x];
    v.y = cb[d * K + iv.y];
    v.z = cb[d * K + iv.z];
    v.w = cb[d * K + iv.w];
    *reinterpret_cast<float4*>(out + o) = v;
}

extern "C" void kernel_launch(void* const* d_in, const int* in_sizes, int n_in,
                              void* d_out, int out_size, void* d_ws, size_t ws_size,
                              hipStream_t stream) {
    const float* enc = (const float*)d_in[0];
    const float* cb  = (const float*)d_in[1];
    float* out = (float*)d_out;
    char* ws = (char*)d_ws;

    if (ws_size >= (size_t)WS_NEED) {
        float*          ck   = (float*)(ws + OFF_CK);
        float*          ckq  = (float*)(ws + OFF_CKQ);
        unsigned short* cbfh = (unsigned short*)(ws + OFF_CBFH);
        unsigned short* cbfl = (unsigned short*)(ws + OFF_CBFL);
        int*            idx  = (int*)(ws + OFF_IDX);
        int*            cnt  = (int*)(ws + OFF_CNT);
        int*            list = (int*)(ws + OFF_LIST);

        vq_prep_m<<<4, 128, 0, stream>>>(cb, ck, ckq, cbfh, cbfl, cnt);
        vq_mfma<<<NPIX / 256, 256, 0, stream>>>(enc, cbfh, cbfl, ckq, idx, cnt, list);
        vq_refine<<<1024, 256, 0, stream>>>(enc, cb, ck, cnt, list, idx);
        vq_out<<<out_size / 1024, 256, 0, stream>>>(cb, idx, out);
    } else {
        float* ck  = (float*)ws;
        int*   idx = (int*)(ws + 2048);
        vq_prep_s<<<1, K, 0, stream>>>(cb, ck);
        vq_main_s<<<NPIX / 64, 256, 0, stream>>>(enc, cb, ck, idx);
        vq_out<<<out_size / 1024, 256, 0, stream>>>(cb, idx, out);
    }
}

// Round 12
// 154.359 us; speedup vs baseline: 1.0374x; 1.0024x over previous
//
#include <hip/hip_runtime.h>
#include <float.h>

#define D    64
#define K    512
#define HW   4096      // 64*64
#define NPIX 131072    // 32*4096
#define KT   16
#define GT_S 1.2e-4f   // gap threshold in s-units; |s_mfma - s_numpy| bound ~1e-5

// ===== MFMA-path ws layout (bytes) =====
#define OFF_CK    0u          // float ck[512]
#define OFF_CBFH  2048u       // ushort cbfh[64*512] frag-packed
#define OFF_CBFL  67584u      // ushort cbfl[64*512]
#define OFF_IDX   34211840u   // int idx[NPIX]
#define OFF_CNT   34736128u   // int count
#define OFF_LIST  34736132u   // int list[NPIX]
#define OFF_CKQ   35260420u   // float ckq[512] = -ck/2
#define WS_NEED   35262468u

typedef __attribute__((ext_vector_type(8))) short bf16x8;
typedef __attribute__((ext_vector_type(4))) float f32x4;

__device__ __forceinline__ unsigned short bf16_rne(float f) {
    unsigned u = __float_as_uint(f);
    return (unsigned short)((u + 0x7FFFu + ((u >> 16) & 1u)) >> 16);
}
__device__ __forceinline__ float bf16_back(unsigned short h) {
    return __uint_as_float(((unsigned)h) << 16);
}

// ck[k] = numpy sum(cb*cb, axis=0): sequential adds over d, squares pre-rounded.
// ckq[k] = -ck/2. Packs cb into bf16 hi/lo fragment layout:
//   pos(tile=k>>4, ks=d>>5, g=(d>>3)&3, n=k&15, j=d&7) = (tile*2+ks)*512 + g*128 + n*8 + j
__global__ void vq_prep_m(const float* __restrict__ cb, float* __restrict__ ck,
                          float* __restrict__ ckq,
                          unsigned short* __restrict__ cbfh, unsigned short* __restrict__ cbfl,
                          int* __restrict__ count) {
#pragma clang fp contract(off)
    const int k = blockIdx.x * 128 + threadIdx.x;
    if (k == 0) *count = 0;
    float s = 0.f;
    for (int d = 0; d < D; ++d) {
        const float e  = cb[d * K + k];
        const float e2 = e * e;
        s = s + e2;
        const unsigned short h = bf16_rne(e);
        const unsigned short l = bf16_rne(e - bf16_back(h));
        const int pos = ((k >> 4) * 2 + (d >> 5)) * 512 + ((d >> 3) & 3) * 128 + (k & 15) * 8 + (d & 7);
        cbfh[pos] = h;
        cbfl[pos] = l;
    }
    ck[k]  = s;
    ckq[k] = -0.5f * s;
}

// MFMA filter v4: 32 px/wave, ALL operands in named scalars, launch_bounds
// (256,4) => 128-VGPR cap, audited footprint ~110 -> NO spill (rounds 10/11
// lesson: hipcc silently caps + spills A-frags to scratch; scratch reads
// serialized into the MFMA chain were the 10x slowdown).
#define CVT_PAIR(HP, LP, F0, F1) do {                                      \
    asm("v_cvt_pk_bf16_f32 %0, %1, %2" : "=v"(HP) : "v"(F0), "v"(F1));     \
    const float _b0 = __uint_as_float((HP) << 16);                         \
    const float _b1 = __uint_as_float((HP) & 0xffff0000u);                 \
    const float _r0 = (F0) - _b0;                                          \
    const float _r1 = (F1) - _b1;                                          \
    asm("v_cvt_pk_bf16_f32 %0, %1, %2" : "=v"(LP) : "v"(_r0), "v"(_r1));   \
} while (0)

#define LOAD_A(PG, KS, H4, L4) do {                                        \
    float r0 = ep[(size_t)((KS) * 32 + g * 8 + 0) * HW + hwp + (PG) * 16]; \
    float r1 = ep[(size_t)((KS) * 32 + g * 8 + 1) * HW + hwp + (PG) * 16]; \
    float r2 = ep[(size_t)((KS) * 32 + g * 8 + 2) * HW + hwp + (PG) * 16]; \
    float r3 = ep[(size_t)((KS) * 32 + g * 8 + 3) * HW + hwp + (PG) * 16]; \
    float r4 = ep[(size_t)((KS) * 32 + g * 8 + 4) * HW + hwp + (PG) * 16]; \
    float r5 = ep[(size_t)((KS) * 32 + g * 8 + 5) * HW + hwp + (PG) * 16]; \
    float r6 = ep[(size_t)((KS) * 32 + g * 8 + 6) * HW + hwp + (PG) * 16]; \
    float r7 = ep[(size_t)((KS) * 32 + g * 8 + 7) * HW + hwp + (PG) * 16]; \
    CVT_PAIR(H4.x, L4.x, r0, r1);                                          \
    CVT_PAIR(H4.y, L4.y, r2, r3);                                          \
    CVT_PAIR(H4.z, L4.z, r4, r5);                                          \
    CVT_PAIR(H4.w, L4.w, r6, r7);                                          \
} while (0)

#define LOADB(S, T) do {                                                   \
    const int _o = (T) * 1024;                                             \
    h0##S = *(const bf16x8*)(cbfh_l + _o);                                 \
    h1##S = *(const bf16x8*)(cbfh_l + _o + 512);                           \
    l0##S = *(const bf16x8*)(cbfl_l + _o);                                 \
    l1##S = *(const bf16x8*)(cbfl_l + _o + 512);                           \
    ck##S = ckq_l[(T) * 16];                                               \
} while (0)

#define TRACK(SL, V) do {                                                  \
    const bool _gt = (V) > best##SL;                                       \
    bi##SL    = _gt ? (T_) : bi##SL;                                       \
    best2##SL = fmaxf(best2##SL, fminf(best##SL, (V)));                    \
    best##SL  = fmaxf(best##SL, (V));                                      \
} while (0)

#define PROCESS(S, T) do {                                                 \
    const int T_ = (T);                                                    \
    const f32x4 CKv = {ck##S, ck##S, ck##S, ck##S};                        \
    f32x4 p0, p1, q0, q1;                                                  \
    p0 = __builtin_amdgcn_mfma_f32_16x16x32_bf16(                          \
            __builtin_bit_cast(bf16x8, al00), h0##S, CKv, 0,0,0);          \
    p0 = __builtin_amdgcn_mfma_f32_16x16x32_bf16(                          \
            __builtin_bit_cast(bf16x8, ah00), l0##S, p0, 0,0,0);           \
    p0 = __builtin_amdgcn_mfma_f32_16x16x32_bf16(                          \
            __builtin_bit_cast(bf16x8, ah00), h0##S, p0, 0,0,0);           \
    p1 = __builtin_amdgcn_mfma_f32_16x16x32_bf16(                          \
            __builtin_bit_cast(bf16x8, al01), h1##S, Z4, 0,0,0);           \
    p1 = __builtin_amdgcn_mfma_f32_16x16x32_bf16(                          \
            __builtin_bit_cast(bf16x8, ah01), l1##S, p1, 0,0,0);           \
    p1 = __builtin_amdgcn_mfma_f32_16x16x32_bf16(                          \
            __builtin_bit_cast(bf16x8, ah01), h1##S, p1, 0,0,0);           \
    q0 = __builtin_amdgcn_mfma_f32_16x16x32_bf16(                          \
            __builtin_bit_cast(bf16x8, al10), h0##S, CKv, 0,0,0);          \
    q0 = __builtin_amdgcn_mfma_f32_16x16x32_bf16(                          \
            __builtin_bit_cast(bf16x8, ah10), l0##S, q0, 0,0,0);           \
    q0 = __builtin_amdgcn_mfma_f32_16x16x32_bf16(                          \
            __builtin_bit_cast(bf16x8, ah10), h0##S, q0, 0,0,0);           \
    q1 = __builtin_amdgcn_mfma_f32_16x16x32_bf16(                          \
            __builtin_bit_cast(bf16x8, al11), h1##S, Z4, 0,0,0);           \
    q1 = __builtin_amdgcn_mfma_f32_16x16x32_bf16(                          \
            __builtin_bit_cast(bf16x8, ah11), l1##S, q1, 0,0,0);           \
    q1 = __builtin_amdgcn_mfma_f32_16x16x32_bf16(                          \
            __builtin_bit_cast(bf16x8, ah11), h1##S, q1, 0,0,0);           \
    TRACK(0, p0[0] + p1[0]);                                               \
    TRACK(1, p0[1] + p1[1]);                                               \
    TRACK(2, p0[2] + p1[2]);                                               \
    TRACK(3, p0[3] + p1[3]);                                               \
    TRACK(4, q0[0] + q1[0]);                                               \
    TRACK(5, q0[1] + q1[1]);                                               \
    TRACK(6, q0[2] + q1[2]);                                               \
    TRACK(7, q0[3] + q1[3]);                                               \
} while (0)

#define MERGE(SL) do {                                                     \
    const float ob  = __shfl_xor(best##SL,  off, 16);                      \
    const float ob2 = __shfl_xor(best2##SL, off, 16);                      \
    const int   obi = __shfl_xor(bi##SL,    off, 16);                      \
    const bool  gt  = ob > best##SL;                                       \
    const float mn  = fminf(best##SL, ob);                                 \
    const float b2w = gt ? ob2 : best2##SL;                                \
    best2##SL = fmaxf(mn, b2w);                                            \
    bi##SL    = gt ? obi : bi##SL;                                         \
    best##SL  = fmaxf(best##SL, ob);                                       \
} while (0)

#define EMIT(SL, PG, I) do {                                               \
    const int p = P0 + (PG) * 16 + g * 4 + (I);                            \
    idx[p] = bi##SL;                                                       \
    if (best##SL - best2##SL < GT_S) {                                     \
        const int slot = atomicAdd(count, 1);                              \
        list[slot] = p;                                                    \
    }                                                                      \
} while (0)

__global__ __launch_bounds__(256, 4) void vq_mfma(const float* __restrict__ enc,
        const unsigned short* __restrict__ cbfh, const unsigned short* __restrict__ cbfl,
        const float* __restrict__ ckq, int* __restrict__ idx,
        int* __restrict__ count, int* __restrict__ list) {
    const int t    = threadIdx.x;
    const int lane = t & 63;
    const int wu   = __builtin_amdgcn_readfirstlane(t >> 6);
    const int P0   = blockIdx.x * 128 + wu * 32;
    const int n    = lane & 15;          // A row = pixel-in-group; B col = code-in-tile
    const int g    = lane >> 4;          // k-chunk / D row group

    // A-frags straight from enc, bf16 hi/lo split in-register (named scalars)
    const float* ep = enc + (size_t)(P0 >> 12) * (D * HW);
    const int hwp = (P0 & 4095) + n;
    uint4 ah00, ah01, ah10, ah11, al00, al01, al10, al11;
    LOAD_A(0, 0, ah00, al00);
    LOAD_A(0, 1, ah01, al01);
    LOAD_A(1, 0, ah10, al10);
    LOAD_A(1, 1, ah11, al11);

    const unsigned short* cbfh_l = cbfh + g * 128 + n * 8;
    const unsigned short* cbfl_l = cbfl + g * 128 + n * 8;
    const float*          ckq_l  = ckq + n;
    const f32x4 Z4 = {0.f, 0.f, 0.f, 0.f};

    float best0, best1, best2_, best3, best4, best5, best6, best7;
    float best20, best21, best22, best23, best24, best25, best26, best27;
    int bi0, bi1, bi2, bi3, bi4, bi5, bi6, bi7;
    best0 = best1 = best2_ = best3 = best4 = best5 = best6 = best7 = -FLT_MAX;
    best20 = best21 = best22 = best23 = best24 = best25 = best26 = best27 = -FLT_MAX;
    bi0 = bi1 = bi2 = bi3 = bi4 = bi5 = bi6 = bi7 = 0;
    // alias so TRACK(2,..) hits best2_ not the runner-up array naming
#define best2 best2_
#define best22_ best22
    // (slot names: bestS / best2S / biS with S in 0..7; best2 of slot2 = best2_)
#undef best2

    bf16x8 h0a, h1a, l0a, l1a; float cka;
    bf16x8 h0b, h1b, l0b, l1b; float ckb;
    LOADB(a, 0);
    #pragma unroll 1
    for (int t2 = 0; t2 < 16; ++t2) {
        const int tA = 2 * t2, tB = 2 * t2 + 1;
        LOADB(b, tB);
        {
            // PROCESS(a, tA) with slot names
            const int T_ = tA;
            const f32x4 CKv = {cka, cka, cka, cka};
            f32x4 p0, p1, q0, q1;
            p0 = __builtin_amdgcn_mfma_f32_16x16x32_bf16(__builtin_bit_cast(bf16x8, al00), h0a, CKv, 0,0,0);
            p0 = __builtin_amdgcn_mfma_f32_16x16x32_bf16(__builtin_bit_cast(bf16x8, ah00), l0a, p0, 0,0,0);
            p0 = __builtin_amdgcn_mfma_f32_16x16x32_bf16(__builtin_bit_cast(bf16x8, ah00), h0a, p0, 0,0,0);
            p1 = __builtin_amdgcn_mfma_f32_16x16x32_bf16(__builtin_bit_cast(bf16x8, al01), h1a, Z4, 0,0,0);
            p1 = __builtin_amdgcn_mfma_f32_16x16x32_bf16(__builtin_bit_cast(bf16x8, ah01), l1a, p1, 0,0,0);
            p1 = __builtin_amdgcn_mfma_f32_16x16x32_bf16(__builtin_bit_cast(bf16x8, ah01), h1a, p1, 0,0,0);
            q0 = __builtin_amdgcn_mfma_f32_16x16x32_bf16(__builtin_bit_cast(bf16x8, al10), h0a, CKv, 0,0,0);
            q0 = __builtin_amdgcn_mfma_f32_16x16x32_bf16(__builtin_bit_cast(bf16x8, ah10), l0a, q0, 0,0,0);
            q0 = __builtin_amdgcn_mfma_f32_16x16x32_bf16(__builtin_bit_cast(bf16x8, ah10), h0a, q0, 0,0,0);
            q1 = __builtin_amdgcn_mfma_f32_16x16x32_bf16(__builtin_bit_cast(bf16x8, al11), h1a, Z4, 0,0,0);
            q1 = __builtin_amdgcn_mfma_f32_16x16x32_bf16(__builtin_bit_cast(bf16x8, ah11), l1a, q1, 0,0,0);
            q1 = __builtin_amdgcn_mfma_f32_16x16x32_bf16(__builtin_bit_cast(bf16x8, ah11), h1a, q1, 0,0,0);
            { const float v = p0[0] + p1[0]; const bool gt = v > best0; bi0 = gt ? T_ : bi0; best20 = fmaxf(best20, fminf(best0, v)); best0 = fmaxf(best0, v); }
            { const float v = p0[1] + p1[1]; const bool gt = v > best1; bi1 = gt ? T_ : bi1; best21 = fmaxf(best21, fminf(best1, v)); best1 = fmaxf(best1, v); }
            { const float v = p0[2] + p1[2]; const bool gt = v > best2_; bi2 = gt ? T_ : bi2; best22 = fmaxf(best22, fminf(best2_, v)); best2_ = fmaxf(best2_, v); }
            { const float v = p0[3] + p1[3]; const bool gt = v > best3; bi3 = gt ? T_ : bi3; best23 = fmaxf(best23, fminf(best3, v)); best3 = fmaxf(best3, v); }
            { const float v = q0[0] + q1[0]; const bool gt = v > best4; bi4 = gt ? T_ : bi4; best24 = fmaxf(best24, fminf(best4, v)); best4 = fmaxf(best4, v); }
            { const float v = q0[1] + q1[1]; const bool gt = v > best5; bi5 = gt ? T_ : bi5; best25 = fmaxf(best25, fminf(best5, v)); best5 = fmaxf(best5, v); }
            { const float v = q0[2] + q1[2]; const bool gt = v > best6; bi6 = gt ? T_ : bi6; best26 = fmaxf(best26, fminf(best6, v)); best6 = fmaxf(best6, v); }
            { const float v = q0[3] + q1[3]; const bool gt = v > best7; bi7 = gt ? T_ : bi7; best27 = fmaxf(best27, fminf(best7, v)); best7 = fmaxf(best7, v); }
        }
        LOADB(a, (tB + 1) & 31);    // wraps to 0 on last iter (never processed)
        {
            // PROCESS(b, tB)
            const int T_ = tB;
            const f32x4 CKv = {ckb, ckb, ckb, ckb};
            f32x4 p0, p1, q0, q1;
            p0 = __builtin_amdgcn_mfma_f32_16x16x32_bf16(__builtin_bit_cast(bf16x8, al00), h0b, CKv, 0,0,0);
            p0 = __builtin_amdgcn_mfma_f32_16x16x32_bf16(__builtin_bit_cast(bf16x8, ah00), l0b, p0, 0,0,0);
            p0 = __builtin_amdgcn_mfma_f32_16x16x32_bf16(__builtin_bit_cast(bf16x8, ah00), h0b, p0, 0,0,0);
            p1 = __builtin_amdgcn_mfma_f32_16x16x32_bf16(__builtin_bit_cast(bf16x8, al01), h1b, Z4, 0,0,0);
            p1 = __builtin_amdgcn_mfma_f32_16x16x32_bf16(__builtin_bit_cast(bf16x8, ah01), l1b, p1, 0,0,0);
            p1 = __builtin_amdgcn_mfma_f32_16x16x32_bf16(__builtin_bit_cast(bf16x8, ah01), h1b, p1, 0,0,0);
            q0 = __builtin_amdgcn_mfma_f32_16x16x32_bf16(__builtin_bit_cast(bf16x8, al10), h0b, CKv, 0,0,0);
            q0 = __builtin_amdgcn_mfma_f32_16x16x32_bf16(__builtin_bit_cast(bf16x8, ah10), l0b, q0, 0,0,0);
            q0 = __builtin_amdgcn_mfma_f32_16x16x32_bf16(__builtin_bit_cast(bf16x8, ah10), h0b, q0, 0,0,0);
            q1 = __builtin_amdgcn_mfma_f32_16x16x32_bf16(__builtin_bit_cast(bf16x8, al11), h1b, Z4, 0,0,0);
            q1 = __builtin_amdgcn_mfma_f32_16x16x32_bf16(__builtin_bit_cast(bf16x8, ah11), l1b, q1, 0,0,0);
            q1 = __builtin_amdgcn_mfma_f32_16x16x32_bf16(__builtin_bit_cast(bf16x8, ah11), h1b, q1, 0,0,0);
            { const float v = p0[0] + p1[0]; const bool gt = v > best0; bi0 = gt ? T_ : bi0; best20 = fmaxf(best20, fminf(best0, v)); best0 = fmaxf(best0, v); }
            { const float v = p0[1] + p1[1]; const bool gt = v > best1; bi1 = gt ? T_ : bi1; best21 = fmaxf(best21, fminf(best1, v)); best1 = fmaxf(best1, v); }
            { const float v = p0[2] + p1[2]; const bool gt = v > best2_; bi2 = gt ? T_ : bi2; best22 = fmaxf(best22, fminf(best2_, v)); best2_ = fmaxf(best2_, v); }
            { const float v = p0[3] + p1[3]; const bool gt = v > best3; bi3 = gt ? T_ : bi3; best23 = fmaxf(best23, fminf(best3, v)); best3 = fmaxf(best3, v); }
            { const float v = q0[0] + q1[0]; const bool gt = v > best4; bi4 = gt ? T_ : bi4; best24 = fmaxf(best24, fminf(best4, v)); best4 = fmaxf(best4, v); }
            { const float v = q0[1] + q1[1]; const bool gt = v > best5; bi5 = gt ? T_ : bi5; best25 = fmaxf(best25, fminf(best5, v)); best5 = fmaxf(best5, v); }
            { const float v = q0[2] + q1[2]; const bool gt = v > best6; bi6 = gt ? T_ : bi6; best26 = fmaxf(best26, fminf(best6, v)); best6 = fmaxf(best6, v); }
            { const float v = q0[3] + q1[3]; const bool gt = v > best7; bi7 = gt ? T_ : bi7; best27 = fmaxf(best27, fminf(best7, v)); best7 = fmaxf(best7, v); }
        }
    }

    // encode full code index k = tile*16 + n, then merge across the 16 lanes
    bi0 = bi0 * 16 + n; bi1 = bi1 * 16 + n; bi2 = bi2 * 16 + n; bi3 = bi3 * 16 + n;
    bi4 = bi4 * 16 + n; bi5 = bi5 * 16 + n; bi6 = bi6 * 16 + n; bi7 = bi7 * 16 + n;
    #pragma unroll
    for (int off = 1; off < 16; off <<= 1) {
        { const float ob = __shfl_xor(best0, off, 16); const float ob2 = __shfl_xor(best20, off, 16); const int obi = __shfl_xor(bi0, off, 16); const bool gt = ob > best0; const float mn = fminf(best0, ob); best20 = fmaxf(mn, gt ? ob2 : best20); bi0 = gt ? obi : bi0; best0 = fmaxf(best0, ob); }
        { const float ob = __shfl_xor(best1, off, 16); const float ob2 = __shfl_xor(best21, off, 16); const int obi = __shfl_xor(bi1, off, 16); const bool gt = ob > best1; const float mn = fminf(best1, ob); best21 = fmaxf(mn, gt ? ob2 : best21); bi1 = gt ? obi : bi1; best1 = fmaxf(best1, ob); }
        { const float ob = __shfl_xor(best2_, off, 16); const float ob2 = __shfl_xor(best22, off, 16); const int obi = __shfl_xor(bi2, off, 16); const bool gt = ob > best2_; const float mn = fminf(best2_, ob); best22 = fmaxf(mn, gt ? ob2 : best22); bi2 = gt ? obi : bi2; best2_ = fmaxf(best2_, ob); }
        { const float ob = __shfl_xor(best3, off, 16); const float ob2 = __shfl_xor(best23, off, 16); const int obi = __shfl_xor(bi3, off, 16); const bool gt = ob > best3; const float mn = fminf(best3, ob); best23 = fmaxf(mn, gt ? ob2 : best23); bi3 = gt ? obi : bi3; best3 = fmaxf(best3, ob); }
        { const float ob = __shfl_xor(best4, off, 16); const float ob2 = __shfl_xor(best24, off, 16); const int obi = __shfl_xor(bi4, off, 16); const bool gt = ob > best4; const float mn = fminf(best4, ob); best24 = fmaxf(mn, gt ? ob2 : best24); bi4 = gt ? obi : bi4; best4 = fmaxf(best4, ob); }
        { const float ob = __shfl_xor(best5, off, 16); const float ob2 = __shfl_xor(best25, off, 16); const int obi = __shfl_xor(bi5, off, 16); const bool gt = ob > best5; const float mn = fminf(best5, ob); best25 = fmaxf(mn, gt ? ob2 : best25); bi5 = gt ? obi : bi5; best5 = fmaxf(best5, ob); }
        { const float ob = __shfl_xor(best6, off, 16); const float ob2 = __shfl_xor(best26, off, 16); const int obi = __shfl_xor(bi6, off, 16); const bool gt = ob > best6; const float mn = fminf(best6, ob); best26 = fmaxf(mn, gt ? ob2 : best26); bi6 = gt ? obi : bi6; best6 = fmaxf(best6, ob); }
        { const float ob = __shfl_xor(best7, off, 16); const float ob2 = __shfl_xor(best27, off, 16); const int obi = __shfl_xor(bi7, off, 16); const bool gt = ob > best7; const float mn = fminf(best7, ob); best27 = fmaxf(mn, gt ? ob2 : best27); bi7 = gt ? obi : bi7; best7 = fmaxf(best7, ob); }
    }

    if (n == 0) {
        { const int p = P0 + 0 * 16 + g * 4 + 0; idx[p] = bi0; if (best0 - best20 < GT_S) { const int s = atomicAdd(count, 1); list[s] = p; } }
        { const int p = P0 + 0 * 16 + g * 4 + 1; idx[p] = bi1; if (best1 - best21 < GT_S) { const int s = atomicAdd(count, 1); list[s] = p; } }
        { const int p = P0 + 0 * 16 + g * 4 + 2; idx[p] = bi2; if (best2_ - best22 < GT_S) { const int s = atomicAdd(count, 1); list[s] = p; } }
        { const int p = P0 + 0 * 16 + g * 4 + 3; idx[p] = bi3; if (best3 - best23 < GT_S) { const int s = atomicAdd(count, 1); list[s] = p; } }
        { const int p = P0 + 1 * 16 + g * 4 + 0; idx[p] = bi4; if (best4 - best24 < GT_S) { const int s = atomicAdd(count, 1); list[s] = p; } }
        { const int p = P0 + 1 * 16 + g * 4 + 1; idx[p] = bi5; if (best5 - best25 < GT_S) { const int s = atomicAdd(count, 1); list[s] = p; } }
        { const int p = P0 + 1 * 16 + g * 4 + 2; idx[p] = bi6; if (best6 - best26 < GT_S) { const int s = atomicAdd(count, 1); list[s] = p; } }
        { const int p = P0 + 1 * 16 + g * 4 + 3; idx[p] = bi7; if (best7 - best27 < GT_S) { const int s = atomicAdd(count, 1); list[s] = p; } }
    }
}

// Exact numpy rescore for near-tie pixels; computes its own numpy-exact t1.
__global__ __launch_bounds__(256) void vq_refine(const float* __restrict__ enc,
        const float* __restrict__ cb, const float* __restrict__ ck,
        const int* __restrict__ count, const int* __restrict__ list,
        int* __restrict__ idx) {
    const int nref = *count;
    const int lane = threadIdx.x & 63;
    const int gw   = (int)((blockIdx.x * blockDim.x + threadIdx.x) >> 6);
    const int nw   = (int)((gridDim.x * blockDim.x) >> 6);
    for (int r = gw; r < nref; r += nw) {
        const int p  = list[r];
        const int b  = p >> 12;
        const int hw = p & 4095;
        const float* xp = enc + (size_t)b * (D * HW) + hw;
        const float xown = xp[(size_t)lane * HW];   // lane holds x[lane]

        // t1: numpy pairwise n=64 path, bit-exact.
        float t1;
        {
#pragma clang fp contract(off)
            const int jl = lane & 7;
            float rj;
            {
                const float v = __shfl(xown, jl);
                rj = v * v;
            }
            #pragma unroll
            for (int i = 1; i < 8; ++i) {
                const float v  = __shfl(xown, i * 8 + jl);
                const float v2 = v * v;
                rj = rj + v2;
            }
            const float a  = rj + __shfl_xor(rj, 1);
            const float bb = a + __shfl_xor(a, 2);
            t1 = bb + __shfl_xor(bb, 4);
        }

        float acc[8];
        #pragma unroll
        for (int j = 0; j < 8; ++j) acc[j] = 0.f;
        const float* cbl = cb + lane * 8;
        #pragma unroll 16
        for (int d = 0; d < D; ++d) {
            const float xd = __shfl(xown, d);
            const float4 c0 = *(const float4*)(cbl + (size_t)d * K);
            const float4 c1 = *(const float4*)(cbl + (size_t)d * K + 4);
            acc[0] = fmaf(xd, c0.x, acc[0]);
            acc[1] = fmaf(xd, c0.y, acc[1]);
            acc[2] = fmaf(xd, c0.z, acc[2]);
            acc[3] = fmaf(xd, c0.w, acc[3]);
            acc[4] = fmaf(xd, c1.x, acc[4]);
            acc[5] = fmaf(xd, c1.y, acc[5]);
            acc[6] = fmaf(xd, c1.z, acc[6]);
            acc[7] = fmaf(xd, c1.w, acc[7]);
        }
        float bv = FLT_MAX;
        int bI = 0x7fffffff;
        #pragma unroll
        for (int j = 0; j < 8; ++j) {
            const float u    = fmaf(-2.0f, acc[j], t1);
            const float dist = u + ck[lane * 8 + j];
            if (dist < bv) { bv = dist; bI = lane * 8 + j; }
        }
        #pragma unroll
        for (int off = 32; off > 0; off >>= 1) {
            const float ov = __shfl_down(bv, off);
            const int   oi = __shfl_down(bI, off);
            if (ov < bv || (ov == bv && oi < bI)) { bv = ov; bI = oi; }
        }
        if (lane == 0) idx[p] = bI;
    }
}

// ===== scalar fallback (round-7, proven 128 us) =====
__global__ void vq_prep_s(const float* __restrict__ cb, float* __restrict__ ck) {
#pragma clang fp contract(off)
    const int k = threadIdx.x;
    float s = 0.f;
    for (int d = 0; d < D; ++d) {
        const float e  = cb[d * K + k];
        const float e2 = e * e;
        s = s + e2;
    }
    ck[k] = s;
}

__global__ __launch_bounds__(256, 8) void vq_main_s(const float* __restrict__ enc,
        const float* __restrict__ cb, const float* __restrict__ ck,
        int* __restrict__ idx) {
    __shared__ float xs[D][64];
    __shared__ float bvs[3][64];
    __shared__ int   bis[3][64];

    const int t    = threadIdx.x;
    const int lane = t & 63;
    const int wu   = __builtin_amdgcn_readfirstlane(t >> 6);
    const int base = blockIdx.x * 64;
    const int b    = base >> 12;
    const int hw0  = base & 4095;
    const float* ep = enc + (size_t)b * (D * HW) + hw0;

    #pragma unroll
    for (int i = 0; i < 16; ++i) {
        const int id  = t + i * 256;
        xs[id >> 6][id & 63] = ep[(size_t)(id >> 6) * HW + (id & 63)];
    }
    __syncthreads();

    float t1;
    {
#pragma clang fp contract(off)
        float r[8];
        #pragma unroll
        for (int j = 0; j < 8; ++j) { const float v = xs[j][lane]; r[j] = v * v; }
        #pragma unroll
        for (int i = 8; i < 64; i += 8) {
            #pragma unroll
            for (int j = 0; j < 8; ++j) {
                const float v = xs[i + j][lane]; const float v2 = v * v; r[j] = r[j] + v2;
            }
        }
        t1 = ((r[0] + r[1]) + (r[2] + r[3])) + ((r[4] + r[5]) + (r[6] + r[7]));
    }

    float best = FLT_MAX;
    int besti  = 0x7fffffff;
    const int kbase = wu * (K / 4);
    #pragma unroll 1
    for (int tt = 0; tt < 8; ++tt) {
        const int k0 = kbase + tt * KT;
        float acc[KT];
        #pragma unroll
        for (int j = 0; j < KT; ++j) acc[j] = 0.f;
        #pragma unroll 8
        for (int d = 0; d < D; ++d) {
            const float xv = xs[d][lane];
            const float* cbrow = cb + d * K + k0;
            #pragma unroll
            for (int j = 0; j < KT; ++j) acc[j] = fmaf(xv, cbrow[j], acc[j]);
        }
        #pragma unroll
        for (int j = 0; j < KT; ++j) {
            const float u    = fmaf(-2.0f, acc[j], t1);
            const float dist = u + ck[k0 + j];
            if (dist < best) { best = dist; besti = k0 + j; }
        }
    }

    if (wu > 0) { bvs[wu - 1][lane] = best; bis[wu - 1][lane] = besti; }
    __syncthreads();
    if (wu == 0) {
        #pragma unroll
        for (int q = 0; q < 3; ++q) {
            const float ov = bvs[q][lane];
            const int   oi = bis[q][lane];
            if (ov < best) { best = ov; besti = oi; }
        }
        idx[base + lane] = besti;
    }
}

__global__ void vq_out(const float* __restrict__ cb, const int* __restrict__ idx,
                       float* __restrict__ out) {
    const int o = (blockIdx.x * 256 + threadIdx.x) * 4;
    const int d = (o >> 12) & 63;
    const int bhw = ((o >> 18) << 12) | (o & 4095);
    const int4 iv = *reinterpret_cast<const int4*>(idx + bhw);
    float4 v;
    v.x = cb[d * K + iv.x];
    v.y = cb[d * K + iv.y];
    v.z = cb[d * K + iv.z];
    v.w = cb[d * K + iv.w];
    *reinterpret_cast<float4*>(out + o) = v;
}

extern "C" void kernel_launch(void* const* d_in, const int* in_sizes, int n_in,
                              void* d_out, int out_size, void* d_ws, size_t ws_size,
                              hipStream_t stream) {
    const float* enc = (const float*)d_in[0];
    const float* cb  = (const float*)d_in[1];
    float* out = (float*)d_out;
    char* ws = (char*)d_ws;

    if (ws_size >= (size_t)WS_NEED) {
        float*          ck   = (float*)(ws + OFF_CK);
        float*          ckq  = (float*)(ws + OFF_CKQ);
        unsigned short* cbfh = (unsigned short*)(ws + OFF_CBFH);
        unsigned short* cbfl = (unsigned short*)(ws + OFF_CBFL);
        int*            idx  = (int*)(ws + OFF_IDX);
        int*            cnt  = (int*)(ws + OFF_CNT);
        int*            list = (int*)(ws + OFF_LIST);

        vq_prep_m<<<4, 128, 0, stream>>>(cb, ck, ckq, cbfh, cbfl, cnt);
        vq_mfma<<<NPIX / 128, 256, 0, stream>>>(enc, cbfh, cbfl, ckq, idx, cnt, list);
        vq_refine<<<1024, 256, 0, stream>>>(enc, cb, ck, cnt, list, idx);
        vq_out<<<out_size / 1024, 256, 0, stream>>>(cb, idx, out);
    } else {
        float* ck  = (float*)ws;
        int*   idx = (int*)(ws + 2048);
        vq_prep_s<<<1, K, 0, stream>>>(cb, ck);
        vq_main_s<<<NPIX / 64, 256, 0, stream>>>(enc, cb, ck, idx);
        vq_out<<<out_size / 1024, 256, 0, stream>>>(cb, idx, out);
    }
}